// Round 4
// baseline (746.532 us; speedup 1.0000x reference)
//
#include <hip/hip_runtime.h>
#include <stdint.h>

typedef _Float16 f16x8 __attribute__((ext_vector_type(8)));
typedef _Float16 f16x4 __attribute__((ext_vector_type(4)));
typedef float fx4 __attribute__((ext_vector_type(4)));

static constexpr int S_LEN = 2048;
static constexpr int BATCH = 2;
static constexpr int TOKENS = BATCH * S_LEN;   // 4096
static constexpr int DIM = 2048;
static constexpr int NH = 16;
static constexpr int QR = 1536;
static constexpr int KVR = 512;
static constexpr int DN = 128;
static constexpr int DR = 64;
static constexpr int DV = 128;

// async global->LDS, 16B per lane; LDS dest = wave-uniform base, HW adds lane*16
__device__ __forceinline__ void async16(const _Float16* g, _Float16* lds_base_uniform) {
  __builtin_amdgcn_global_load_lds(
      (const __attribute__((address_space(1))) void*)g,
      (__attribute__((address_space(3))) void*)lds_base_uniform, 16, 0, 0);
}

// ---------------- fused f32 -> f16 conversion (all tensors, one dispatch) ---
struct CvtSegs {
  const float* src[8];
  _Float16* dst[8];
  int n4[8];
  int cum[9];
};
__global__ __launch_bounds__(256) void cvt_all(CvtSegs s) {
  const int b = blockIdx.x;
  int seg = 0;
#pragma unroll
  for (int k = 0; k < 7; ++k) seg += (b >= s.cum[seg + 1]) ? 1 : 0;
  const int i = (b - s.cum[seg]) * 256 + threadIdx.x;
  if (i >= s.n4[seg]) return;
  fx4 v = *(const fx4*)(s.src[seg] + (size_t)i * 4);
  f16x4 o;
  o[0] = (_Float16)v[0]; o[1] = (_Float16)v[1];
  o[2] = (_Float16)v[2]; o[3] = (_Float16)v[3];
  *(f16x4*)(s.dst[seg] + (size_t)i * 4) = o;
}

// ---------------- NT GEMM, dbuf LDS, one barrier/K-iter, TM x 128 tile -----
// C[M,N] = A[M,K] * W[N,K]^T.
// MODE 1: f32 C0 (TM=64).  MODE 2: split knope[T,2048] + vT[2048,T] (TM=128).
// MODE 3: split qnope[.,2048] + qpe[.,1024] (TM=128).
// MODE 5: down-fused split qc[.,1536] | kvc[.,512] | krope[.,64] (TM=64, N=2112).
template <int MODE, int TM>
__global__ __launch_bounds__(256, TM == 64 ? 4 : 1)
void gemm_nt(const _Float16* __restrict__ A, const _Float16* __restrict__ W,
             void* __restrict__ C0v, void* __restrict__ C1v, void* __restrict__ C2v,
             int N, int K) {
  constexpr int NI = TM / 32;                 // acc tiles in M per wave
  __shared__ __attribute__((aligned(16))) _Float16 As[2][TM * 32];
  __shared__ __attribute__((aligned(16))) _Float16 Ws[2][128 * 32];
  const int tid = threadIdx.x;
  const int lane = tid & 63;
  const int wave = tid >> 6;
  const int wr = (wave >> 1) * (TM / 2);
  const int wc = (wave & 1) * 64;
  const int m16 = lane & 15;
  const int quad = lane >> 4;
  const int m0 = blockIdx.y * TM;
  const int n0 = blockIdx.x * 128;

  auto stage = [&](int buf, int k0) {
#pragma unroll
    for (int p = 0; p < TM / 64; ++p) {       // A: TM*4 chunks of 16B
      const int cb = p * 256 + wave * 64;
      const int ch = cb + lane;
      const int r = ch >> 2;
      const int c8 = (ch & 3) * 8;
      async16(A + (size_t)(m0 + r) * K + k0 + c8, &As[buf][cb * 8]);
    }
#pragma unroll
    for (int p = 0; p < 2; ++p) {             // W: 512 chunks
      const int cb = p * 256 + wave * 64;
      const int ch = cb + lane;
      const int r = ch >> 2;
      const int c8 = (ch & 3) * 8;
      async16(W + (size_t)(n0 + r) * K + k0 + c8, &Ws[buf][cb * 8]);
    }
  };

  const fx4 fz = {0.f, 0.f, 0.f, 0.f};
  fx4 acc[NI][4];
#pragma unroll
  for (int i = 0; i < NI; ++i)
#pragma unroll
    for (int j = 0; j < 4; ++j) acc[i][j] = fz;

  const int nkt = K >> 5;
  stage(0, 0);
  for (int kt = 0; kt < nkt; ++kt) {
    __syncthreads();
    if (kt + 1 < nkt) stage((kt + 1) & 1, (kt + 1) * 32);
    const _Float16* as = As[kt & 1];
    const _Float16* ws = Ws[kt & 1];
    f16x8 af[NI], wf[4];
#pragma unroll
    for (int i = 0; i < NI; ++i)
      af[i] = *(const f16x8*)(&as[(wr + i * 16 + m16) * 32 + quad * 8]);
#pragma unroll
    for (int j = 0; j < 4; ++j)
      wf[j] = *(const f16x8*)(&ws[(wc + j * 16 + m16) * 32 + quad * 8]);
#pragma unroll
    for (int i = 0; i < NI; ++i)
#pragma unroll
      for (int j = 0; j < 4; ++j)
        acc[i][j] = __builtin_amdgcn_mfma_f32_16x16x32_f16(af[i], wf[j], acc[i][j], 0, 0, 0);
  }

#pragma unroll
  for (int j = 0; j < 4; ++j) {
    const int col = n0 + wc + j * 16 + m16;
    if (MODE == 2) {
      _Float16* KN = (_Float16*)C0v;
      _Float16* VT = (_Float16*)C1v;
      const int head = col >> 8;
      const int sub = col & 255;
      if (sub < 128) {
#pragma unroll
        for (int i = 0; i < NI; ++i)
#pragma unroll
          for (int r = 0; r < 4; ++r)
            KN[(size_t)(m0 + wr + i * 16 + quad * 4 + r) * 2048 + head * 128 + sub] =
                (_Float16)acc[i][j][r];
      } else {
        const int dv = sub - 128;
#pragma unroll
        for (int i = 0; i < NI; ++i) {
          f16x4 v;
#pragma unroll
          for (int r = 0; r < 4; ++r) v[r] = (_Float16)acc[i][j][r];
          *(f16x4*)(&VT[(size_t)(head * 128 + dv) * TOKENS + m0 + wr + i * 16 + quad * 4]) = v;
        }
      }
    } else if (MODE == 3) {
#pragma unroll
      for (int i = 0; i < NI; ++i)
#pragma unroll
        for (int r = 0; r < 4; ++r) {
          const size_t row = (size_t)(m0 + wr + i * 16 + quad * 4 + r);
          if (col < 2048) ((_Float16*)C0v)[row * 2048 + col] = (_Float16)acc[i][j][r];
          else ((_Float16*)C1v)[row * 1024 + col - 2048] = (_Float16)acc[i][j][r];
        }
    } else if (MODE == 5) {
#pragma unroll
      for (int i = 0; i < NI; ++i)
#pragma unroll
        for (int r = 0; r < 4; ++r) {
          const size_t row = (size_t)(m0 + wr + i * 16 + quad * 4 + r);
          const _Float16 v = (_Float16)acc[i][j][r];
          if (col < 1536) ((_Float16*)C0v)[row * 1536 + col] = v;
          else if (col < 2048) ((_Float16*)C1v)[row * 512 + col - 1536] = v;
          else if (col < 2112) ((_Float16*)C2v)[row * 64 + col - 2048] = v;
        }
    } else {  // MODE 1: f32
      if (col < N) {
#pragma unroll
        for (int i = 0; i < NI; ++i)
#pragma unroll
          for (int r = 0; r < 4; ++r) {
            const size_t row = (size_t)(m0 + wr + i * 16 + quad * 4 + r);
            ((float*)C0v)[row * N + col] = acc[i][j][r];
          }
      }
    }
  }
}

// ---------------- in-place RMSNorm over f16 rows (fp32 math) ---------------
template <int NC>
__global__ __launch_bounds__(256) void rmsnorm_ip(_Float16* __restrict__ xx,
                                                  const float* __restrict__ w) {
  const int row = blockIdx.x;
  _Float16* p = xx + (size_t)row * NC;
  float ss = 0.f;
  for (int c = threadIdx.x; c < NC; c += 256) {
    const float v = (float)p[c];
    ss += v * v;
  }
#pragma unroll
  for (int d = 1; d < 64; d <<= 1) ss += __shfl_xor(ss, d);
  __shared__ float red[4];
  if ((threadIdx.x & 63) == 0) red[threadIdx.x >> 6] = ss;
  __syncthreads();
  const float rs = rsqrtf((red[0] + red[1] + red[2] + red[3]) * (1.0f / NC) + 1e-6f);
  for (int c = threadIdx.x; c < NC; c += 256)
    p[c] = (_Float16)((float)p[c] * rs * w[c]);
}

// ---------------- in-place RoPE (LLaMA interleaved pairs, d=64) ------------
__global__ void rope_q(_Float16* __restrict__ qpe) {  // [T, NH*64]
  const int idx = blockIdx.x * 256 + threadIdx.x;     // T*NH*32 threads
  const int t = idx >> 9;
  const int rem = idx & 511;
  const int hh = rem >> 5;
  const int i = rem & 31;
  const int s = t & (S_LEN - 1);
  const float fr = exp2f(-(float)i * 0.4152410118609203f);  // log2(1e4)/32
  const float ang = (float)s * fr;
  const float sn = sinf(ang), cs = cosf(ang);
  const size_t base = (size_t)t * (NH * DR) + hh * DR + 2 * i;
  const float x1 = (float)qpe[base];
  const float x2 = (float)qpe[base + 1];
  qpe[base] = (_Float16)(x1 * cs - x2 * sn);
  qpe[base + 1] = (_Float16)(x1 * sn + x2 * cs);
}

__global__ void rope_k(_Float16* __restrict__ kr) {  // [T, 64]
  const int idx = blockIdx.x * 256 + threadIdx.x;    // T*32 threads
  const int t = idx >> 5;
  const int i = idx & 31;
  const int s = t & (S_LEN - 1);
  const float fr = exp2f(-(float)i * 0.4152410118609203f);
  const float ang = (float)s * fr;
  const float sn = sinf(ang), cs = cosf(ang);
  const size_t base = (size_t)t * DR + 2 * i;
  const float x1 = (float)kr[base];
  const float x2 = (float)kr[base + 1];
  kr[base] = (_Float16)(x1 * cs - x2 * sn);
  kr[base + 1] = (_Float16)(x1 * sn + x2 * cs);
}

// ---------------- causal flash attention v4 --------------------------------
// Block = 4 waves x 16 q-rows = 64 q-rows. Grid 1024 -> 4 blocks/CU
// (4 waves/SIMD). 32-key K-tiles in LDS (chunk-major, global_load_lds,
// double-buffered, ONE barrier/tile). V direct global->reg (issued before
// the prefetch so vmcnt ordering doesn't drain the prefetch). P transpose
// via wave-private LDS. Scale pre-folded into Q.
__global__ __launch_bounds__(256, 4) void mla_attn(
    const _Float16* __restrict__ qn,   // [T, NH*128]
    const _Float16* __restrict__ qp,   // [T, NH*64]  roped
    const _Float16* __restrict__ kn,   // [T, NH*128]
    const _Float16* __restrict__ kr,   // [T, 64]     roped
    const _Float16* __restrict__ vT,   // [NH*128, T]
    _Float16* __restrict__ out)        // [T, NH*128]
{
  __shared__ __attribute__((aligned(16))) _Float16 Ks[2][768 * 8];
  __shared__ __attribute__((aligned(16))) _Float16 Ps[4][16][40];

  const int bid = blockIdx.x;
  const int b = bid >> 9;
  const int u = bid & 511;
  const int h = u >> 5;
  const int xq = u & 31;
  const int q32 = b ? (31 - xq) : xq;   // complementary pairing across batches
  const int qb = q32 * 64;
  const int tok0 = b * S_LEN;

  const int tid = threadIdx.x;
  const int lane = tid & 63;
  const int wave = tid >> 6;
  const int m16 = lane & 15;
  const int quad = lane >> 4;
  const int R0 = qb + wave * 16;        // this wave's first q-row

  auto stageK = [&](int buf, int kbase) {
#pragma unroll
    for (int j = 0; j < 3; ++j) {
      const int i = wave * 3 + j;             // instr 0..11
      const int ch = i * 2 + (lane >> 5);     // wave-uniform side of 16
      const int key = lane & 31;
      const _Float16* g = (ch < 16)
          ? kn + (size_t)(tok0 + kbase + key) * 2048 + h * 128 + ch * 8
          : kr + (size_t)(tok0 + kbase + key) * 64 + (ch - 16) * 8;
      async16(g, &Ks[buf][i * 512]);
    }
  };

  // ---- Q fragments (A-layout), scale pre-folded ----
  const _Float16 hscale = (_Float16)0.07216878364870323f;  // 1/sqrt(192)
  f16x8 qf[6];
  {
    const size_t t = (size_t)(tok0 + R0 + m16);
#pragma unroll
    for (int kk = 0; kk < 4; ++kk)
      qf[kk] = *(const f16x8*)(qn + t * 2048 + h * 128 + kk * 32 + quad * 8);
#pragma unroll
    for (int kk = 0; kk < 2; ++kk)
      qf[4 + kk] = *(const f16x8*)(qp + t * 1024 + h * 64 + kk * 32 + quad * 8);
#pragma unroll
    for (int kk = 0; kk < 6; ++kk)
#pragma unroll
      for (int z = 0; z < 8; ++z) qf[kk][z] = qf[kk][z] * hscale;
  }

  const fx4 fz = {0.f, 0.f, 0.f, 0.f};
  fx4 oacc[8];
#pragma unroll
  for (int n = 0; n < 8; ++n) oacc[n] = fz;
  float mst[4], lst[4];
#pragma unroll
  for (int r = 0; r < 4; ++r) { mst[r] = -3.0e38f; lst[r] = 0.f; }

  const int nkt = qb / 32 + 2;               // key tiles: 0 .. qb+63

  stageK(0, 0);
  for (int kt = 0; kt < nkt; ++kt) {
    const int kbase = kt * 32;
    __syncthreads();                          // buf[kt&1] ready (in flight last iter)
    const bool live = (kbase <= R0 + 15);

    // V loads BEFORE prefetch-issue (vmcnt completes in order)
    f16x8 vf[8];
    if (live) {
#pragma unroll
      for (int n8 = 0; n8 < 8; ++n8)
        vf[n8] = *(const f16x8*)(vT + (size_t)(h * 128 + n8 * 16 + m16) * TOKENS +
                                 tok0 + kbase + quad * 8);
    }
    if (kt + 1 < nkt) stageK((kt + 1) & 1, kbase + 32);

    if (!live) continue;                      // fully-masked tile for this wave
    const _Float16* ks = Ks[kt & 1];

    // ---- S = Q K^T : 16 rows x 32 keys ----
    fx4 sc0 = fz, sc1 = fz;
#pragma unroll
    for (int kk = 0; kk < 6; ++kk) {
      f16x8 kf0 = *(const f16x8*)(&ks[((kk * 4 + quad) * 32 + m16) * 8]);
      f16x8 kf1 = *(const f16x8*)(&ks[((kk * 4 + quad) * 32 + 16 + m16) * 8]);
      sc0 = __builtin_amdgcn_mfma_f32_16x16x32_f16(qf[kk], kf0, sc0, 0, 0, 0);
      sc1 = __builtin_amdgcn_mfma_f32_16x16x32_f16(qf[kk], kf1, sc1, 0, 0, 0);
    }

    // ---- online softmax (C/D layout: row = quad*4+r, col = n*16+m16) ----
    const bool needmask = (kbase + 31 > R0);
    float alpha[4];
#pragma unroll
    for (int r = 0; r < 4; ++r) {
      float v0 = sc0[r];
      float v1 = sc1[r];
      if (needmask) {
        const int qrow = R0 + quad * 4 + r;
        if (kbase + m16 > qrow)      v0 = -3.0e38f;
        if (kbase + 16 + m16 > qrow) v1 = -3.0e38f;
      }
      float mx = fmaxf(v0, v1);
#pragma unroll
      for (int d = 1; d < 16; d <<= 1) mx = fmaxf(mx, __shfl_xor(mx, d));
      const float mn = fmaxf(mst[r], mx);
      const float al = __expf(mst[r] - mn);
      const float p0 = __expf(v0 - mn);
      const float p1 = __expf(v1 - mn);
      float ls = p0 + p1;
#pragma unroll
      for (int d = 1; d < 16; d <<= 1) ls += __shfl_xor(ls, d);
      mst[r] = mn;
      lst[r] = lst[r] * al + ls;
      alpha[r] = al;
      _Float16* pr = &Ps[wave][quad * 4 + r][0];
      pr[m16] = (_Float16)p0;
      pr[16 + m16] = (_Float16)p1;
    }
#pragma unroll
    for (int n8 = 0; n8 < 8; ++n8)
#pragma unroll
      for (int r = 0; r < 4; ++r) oacc[n8][r] *= alpha[r];

    // ---- O += P V  (P via wave-private LDS -> A-layout; V from regs) ----
    f16x8 pf = *(const f16x8*)(&Ps[wave][m16][quad * 8]);
#pragma unroll
    for (int n8 = 0; n8 < 8; ++n8)
      oacc[n8] = __builtin_amdgcn_mfma_f32_16x16x32_f16(pf, vf[n8], oacc[n8], 0, 0, 0);
  }

  // ---- epilogue ----
  float inv[4];
#pragma unroll
  for (int r = 0; r < 4; ++r) inv[r] = 1.0f / lst[r];
#pragma unroll
  for (int n8 = 0; n8 < 8; ++n8) {
#pragma unroll
    for (int r = 0; r < 4; ++r) {
      const size_t t = (size_t)(tok0 + R0 + quad * 4 + r);
      out[t * 2048 + h * 128 + n8 * 16 + m16] = (_Float16)(oacc[n8][r] * inv[r]);
    }
  }
}

// ---------------- launch ----------------------------------------------------
extern "C" void kernel_launch(void* const* d_in, const int* in_sizes, int n_in,
                              void* d_out, int out_size, void* d_ws, size_t ws_size,
                              hipStream_t stream) {
  const float* x         = (const float*)d_in[0];
  const float* wq_down   = (const float*)d_in[1];
  const float* q_norm_w  = (const float*)d_in[2];
  const float* wq_up     = (const float*)d_in[3];
  const float* wq_rope   = (const float*)d_in[4];
  const float* wkv_down  = (const float*)d_in[5];
  const float* kv_norm_w = (const float*)d_in[6];
  const float* wkv_up    = (const float*)d_in[7];
  const float* wk_rope   = (const float*)d_in[8];
  const float* wo        = (const float*)d_in[9];
  float* out = (float*)d_out;

  char* ws = (char*)d_ws;
  size_t off = 0;
  auto alloc = [&](size_t bytes) {
    char* p = ws + off;
    off += (bytes + 255) & ~(size_t)255;
    return p;
  };
  _Float16* x_h     = (_Float16*)alloc((size_t)TOKENS * DIM * 2);
  _Float16* wdown_h = (_Float16*)alloc((size_t)2176 * DIM * 2);  // wqd|wkvd|wkr + 64 pad rows
  _Float16* wquqr_h = (_Float16*)alloc((size_t)3072 * QR * 2);   // wq_up | wq_rope
  _Float16* wkvu_h  = (_Float16*)alloc((size_t)NH * 256 * KVR * 2);
  _Float16* wo_h    = (_Float16*)alloc((size_t)DIM * NH * DV * 2);
  _Float16* qc_h    = (_Float16*)alloc((size_t)TOKENS * QR * 2);
  _Float16* kvc_h   = (_Float16*)alloc((size_t)TOKENS * KVR * 2);
  _Float16* qnope_h = (_Float16*)alloc((size_t)TOKENS * 2048 * 2);
  _Float16* qpe_h   = (_Float16*)alloc((size_t)TOKENS * 1024 * 2);
  _Float16* knope_h = (_Float16*)alloc((size_t)TOKENS * 2048 * 2);
  _Float16* vT_h    = (_Float16*)alloc((size_t)2048 * TOKENS * 2);
  _Float16* krope_h = (_Float16*)alloc((size_t)TOKENS * DR * 2);
  _Float16* attn_h  = (_Float16*)alloc((size_t)TOKENS * 2048 * 2);

  // ---- one fused conversion dispatch ----
  CvtSegs cs;
  const float* srcs[8] = {x, wq_down, wkv_down, wk_rope, wq_up, wq_rope, wkv_up, wo};
  _Float16* dsts[8] = {x_h, wdown_h, wdown_h + (size_t)1536 * DIM,
                       wdown_h + (size_t)2048 * DIM, wquqr_h,
                       wquqr_h + (size_t)2048 * QR, wkvu_h, wo_h};
  const size_t ns[8] = {(size_t)TOKENS * DIM, (size_t)QR * DIM, (size_t)KVR * DIM,
                        (size_t)DR * DIM, (size_t)2048 * QR, (size_t)1024 * QR,
                        (size_t)NH * 256 * KVR, (size_t)DIM * NH * DV};
  int cum = 0;
  for (int i = 0; i < 8; ++i) {
    cs.src[i] = srcs[i];
    cs.dst[i] = dsts[i];
    cs.n4[i] = (int)(ns[i] / 4);
    cs.cum[i] = cum;
    cum += (cs.n4[i] + 255) / 256;
  }
  cs.cum[8] = cum;
  cvt_all<<<dim3(cum), 256, 0, stream>>>(cs);

  // down-fused: x -> qc | kvc | krope   (N=2112 in 17 tiles, 64-row M-tiles)
  gemm_nt<5, 64><<<dim3(17, TOKENS / 64), 256, 0, stream>>>(
      x_h, wdown_h, qc_h, kvc_h, krope_h, 2112, DIM);
  rmsnorm_ip<QR><<<dim3(TOKENS), 256, 0, stream>>>(qc_h, q_norm_w);
  rmsnorm_ip<KVR><<<dim3(TOKENS), 256, 0, stream>>>(kvc_h, kv_norm_w);
  rope_k<<<dim3(TOKENS * 32 / 256), 256, 0, stream>>>(krope_h);
  // q up fused: qc -> qnope | qpe (N=3072)
  gemm_nt<3, 128><<<dim3(24, TOKENS / 128), 256, 0, stream>>>(
      qc_h, wquqr_h, qnope_h, qpe_h, nullptr, 3072, QR);
  rope_q<<<dim3(TOKENS * NH * 32 / 256), 256, 0, stream>>>(qpe_h);
  // kv up-projection, split epilogue: k_nope natural + V transposed
  gemm_nt<2, 128><<<dim3(32, TOKENS / 128), 256, 0, stream>>>(
      kvc_h, wkvu_h, knope_h, vT_h, nullptr, 4096, KVR);
  // attention (grid 1024 -> 4 blocks/CU)
  mla_attn<<<dim3(1024), 256, 0, stream>>>(qnope_h, qpe_h, knope_h, krope_h, vT_h, attn_h);
  // output projection (fp32 out, 64-row M-tiles -> grid 1024)
  gemm_nt<1, 64><<<dim3(16, TOKENS / 64), 256, 0, stream>>>(
      attn_h, wo_h, out, nullptr, nullptr, 2048, DIM);
}

// Round 5
// 682.667 us; speedup vs baseline: 1.0936x; 1.0936x over previous
//
#include <hip/hip_runtime.h>
#include <stdint.h>

typedef _Float16 f16x8 __attribute__((ext_vector_type(8)));
typedef _Float16 f16x4 __attribute__((ext_vector_type(4)));
typedef float fx4 __attribute__((ext_vector_type(4)));

static constexpr int S_LEN = 2048;
static constexpr int BATCH = 2;
static constexpr int TOKENS = BATCH * S_LEN;   // 4096
static constexpr int DIM = 2048;
static constexpr int NH = 16;
static constexpr int QR = 1536;
static constexpr int KVR = 512;
static constexpr int DN = 128;
static constexpr int DR = 64;
static constexpr int DV = 128;

// async global->LDS, 16B per lane; LDS dest = wave-uniform base, HW adds lane*16
__device__ __forceinline__ void async16(const _Float16* g, _Float16* lds_base_uniform) {
  __builtin_amdgcn_global_load_lds(
      (const __attribute__((address_space(1))) void*)g,
      (__attribute__((address_space(3))) void*)lds_base_uniform, 16, 0, 0);
}

// ---------------- fused f32 -> f16 conversion (all tensors, one dispatch) ---
struct CvtSegs {
  const float* src[8];
  _Float16* dst[8];
  int n4[8];
  int cum[9];
};
__global__ __launch_bounds__(256) void cvt_all(CvtSegs s) {
  const int b = blockIdx.x;
  int seg = 0;
#pragma unroll
  for (int k = 0; k < 7; ++k) seg += (b >= s.cum[seg + 1]) ? 1 : 0;
  const int i = (b - s.cum[seg]) * 256 + threadIdx.x;
  if (i >= s.n4[seg]) return;
  fx4 v = *(const fx4*)(s.src[seg] + (size_t)i * 4);
  f16x4 o;
  o[0] = (_Float16)v[0]; o[1] = (_Float16)v[1];
  o[2] = (_Float16)v[2]; o[3] = (_Float16)v[3];
  *(f16x4*)(s.dst[seg] + (size_t)i * 4) = o;
}

// ---------------- NT GEMM, dbuf LDS, one barrier/K-iter, TM x 128 tile -----
// C[M,N] = A[M,K] * W[N,K]^T.
// MODE 1: f32 C0 (TM=64).  MODE 2: split knope[T,2048] + vT[2048,T] (TM=128).
// MODE 3: split qnope[.,2048] + qpe[.,1024] (TM=128).
// MODE 5: down-fused split qc[.,1536] | kvc[.,512] | krope[.,64] (TM=64, N=2112).
// NOTE: no min-waves hint — forcing 4 waves/EU in R4 crushed VGPRs to 64 and
// spilled (WRITE_SIZE 109 MB). Natural allocation <=128 gives 4 blocks/CU anyway.
template <int MODE, int TM>
__global__ __launch_bounds__(256)
void gemm_nt(const _Float16* __restrict__ A, const _Float16* __restrict__ W,
             void* __restrict__ C0v, void* __restrict__ C1v, void* __restrict__ C2v,
             int N, int K) {
  constexpr int NI = TM / 32;                 // acc tiles in M per wave
  __shared__ __attribute__((aligned(16))) _Float16 As[2][TM * 32];
  __shared__ __attribute__((aligned(16))) _Float16 Ws[2][128 * 32];
  const int tid = threadIdx.x;
  const int lane = tid & 63;
  const int wave = tid >> 6;
  const int wr = (wave >> 1) * (TM / 2);
  const int wc = (wave & 1) * 64;
  const int m16 = lane & 15;
  const int quad = lane >> 4;
  const int m0 = blockIdx.y * TM;
  const int n0 = blockIdx.x * 128;

  auto stage = [&](int buf, int k0) {
#pragma unroll
    for (int p = 0; p < TM / 64; ++p) {       // A: TM*4 chunks of 16B
      const int cb = p * 256 + wave * 64;
      const int ch = cb + lane;
      const int r = ch >> 2;
      const int c8 = (ch & 3) * 8;
      async16(A + (size_t)(m0 + r) * K + k0 + c8, &As[buf][cb * 8]);
    }
#pragma unroll
    for (int p = 0; p < 2; ++p) {             // W: 512 chunks
      const int cb = p * 256 + wave * 64;
      const int ch = cb + lane;
      const int r = ch >> 2;
      const int c8 = (ch & 3) * 8;
      async16(W + (size_t)(n0 + r) * K + k0 + c8, &Ws[buf][cb * 8]);
    }
  };

  const fx4 fz = {0.f, 0.f, 0.f, 0.f};
  fx4 acc[NI][4];
#pragma unroll
  for (int i = 0; i < NI; ++i)
#pragma unroll
    for (int j = 0; j < 4; ++j) acc[i][j] = fz;

  const int nkt = K >> 5;
  stage(0, 0);
  for (int kt = 0; kt < nkt; ++kt) {
    __syncthreads();
    if (kt + 1 < nkt) stage((kt + 1) & 1, (kt + 1) * 32);
    const _Float16* as = As[kt & 1];
    const _Float16* ws = Ws[kt & 1];
    f16x8 af[NI], wf[4];
#pragma unroll
    for (int i = 0; i < NI; ++i)
      af[i] = *(const f16x8*)(&as[(wr + i * 16 + m16) * 32 + quad * 8]);
#pragma unroll
    for (int j = 0; j < 4; ++j)
      wf[j] = *(const f16x8*)(&ws[(wc + j * 16 + m16) * 32 + quad * 8]);
#pragma unroll
    for (int i = 0; i < NI; ++i)
#pragma unroll
      for (int j = 0; j < 4; ++j)
        acc[i][j] = __builtin_amdgcn_mfma_f32_16x16x32_f16(af[i], wf[j], acc[i][j], 0, 0, 0);
  }

#pragma unroll
  for (int j = 0; j < 4; ++j) {
    const int col = n0 + wc + j * 16 + m16;
    if (MODE == 2) {
      _Float16* KN = (_Float16*)C0v;
      _Float16* VT = (_Float16*)C1v;
      const int head = col >> 8;
      const int sub = col & 255;
      if (sub < 128) {
#pragma unroll
        for (int i = 0; i < NI; ++i)
#pragma unroll
          for (int r = 0; r < 4; ++r)
            KN[(size_t)(m0 + wr + i * 16 + quad * 4 + r) * 2048 + head * 128 + sub] =
                (_Float16)acc[i][j][r];
      } else {
        const int dv = sub - 128;
#pragma unroll
        for (int i = 0; i < NI; ++i) {
          f16x4 v;
#pragma unroll
          for (int r = 0; r < 4; ++r) v[r] = (_Float16)acc[i][j][r];
          *(f16x4*)(&VT[(size_t)(head * 128 + dv) * TOKENS + m0 + wr + i * 16 + quad * 4]) = v;
        }
      }
    } else if (MODE == 3) {
#pragma unroll
      for (int i = 0; i < NI; ++i)
#pragma unroll
        for (int r = 0; r < 4; ++r) {
          const size_t row = (size_t)(m0 + wr + i * 16 + quad * 4 + r);
          if (col < 2048) ((_Float16*)C0v)[row * 2048 + col] = (_Float16)acc[i][j][r];
          else ((_Float16*)C1v)[row * 1024 + col - 2048] = (_Float16)acc[i][j][r];
        }
    } else if (MODE == 5) {
#pragma unroll
      for (int i = 0; i < NI; ++i)
#pragma unroll
        for (int r = 0; r < 4; ++r) {
          const size_t row = (size_t)(m0 + wr + i * 16 + quad * 4 + r);
          const _Float16 v = (_Float16)acc[i][j][r];
          if (col < 1536) ((_Float16*)C0v)[row * 1536 + col] = v;
          else if (col < 2048) ((_Float16*)C1v)[row * 512 + col - 1536] = v;
          else if (col < 2112) ((_Float16*)C2v)[row * 64 + col - 2048] = v;
        }
    } else {  // MODE 1: f32
      if (col < N) {
#pragma unroll
        for (int i = 0; i < NI; ++i)
#pragma unroll
          for (int r = 0; r < 4; ++r) {
            const size_t row = (size_t)(m0 + wr + i * 16 + quad * 4 + r);
            ((float*)C0v)[row * N + col] = acc[i][j][r];
          }
      }
    }
  }
}

// ---------------- in-place RMSNorm over f16 rows (fp32 math) ---------------
template <int NC>
__global__ __launch_bounds__(256) void rmsnorm_ip(_Float16* __restrict__ xx,
                                                  const float* __restrict__ w) {
  const int row = blockIdx.x;
  _Float16* p = xx + (size_t)row * NC;
  float ss = 0.f;
  for (int c = threadIdx.x; c < NC; c += 256) {
    const float v = (float)p[c];
    ss += v * v;
  }
#pragma unroll
  for (int d = 1; d < 64; d <<= 1) ss += __shfl_xor(ss, d);
  __shared__ float red[4];
  if ((threadIdx.x & 63) == 0) red[threadIdx.x >> 6] = ss;
  __syncthreads();
  const float rs = rsqrtf((red[0] + red[1] + red[2] + red[3]) * (1.0f / NC) + 1e-6f);
  for (int c = threadIdx.x; c < NC; c += 256)
    p[c] = (_Float16)((float)p[c] * rs * w[c]);
}

// ---------------- in-place RoPE (LLaMA interleaved pairs, d=64) ------------
__global__ void rope_q(_Float16* __restrict__ qpe) {  // [T, NH*64]
  const int idx = blockIdx.x * 256 + threadIdx.x;     // T*NH*32 threads
  const int t = idx >> 9;
  const int rem = idx & 511;
  const int hh = rem >> 5;
  const int i = rem & 31;
  const int s = t & (S_LEN - 1);
  const float fr = exp2f(-(float)i * 0.4152410118609203f);  // log2(1e4)/32
  const float ang = (float)s * fr;
  const float sn = sinf(ang), cs = cosf(ang);
  const size_t base = (size_t)t * (NH * DR) + hh * DR + 2 * i;
  const float x1 = (float)qpe[base];
  const float x2 = (float)qpe[base + 1];
  qpe[base] = (_Float16)(x1 * cs - x2 * sn);
  qpe[base + 1] = (_Float16)(x1 * sn + x2 * cs);
}

__global__ void rope_k(_Float16* __restrict__ kr) {  // [T, 64]
  const int idx = blockIdx.x * 256 + threadIdx.x;    // T*32 threads
  const int t = idx >> 5;
  const int i = idx & 31;
  const int s = t & (S_LEN - 1);
  const float fr = exp2f(-(float)i * 0.4152410118609203f);
  const float ang = (float)s * fr;
  const float sn = sinf(ang), cs = cosf(ang);
  const size_t base = (size_t)t * DR + 2 * i;
  const float x1 = (float)kr[base];
  const float x2 = (float)kr[base + 1];
  kr[base] = (_Float16)(x1 * cs - x2 * sn);
  kr[base + 1] = (_Float16)(x1 * sn + x2 * cs);
}

// ---------------- causal flash attention v5 --------------------------------
// Block = 4 waves x 16 q-rows = 64 q-rows. Grid 1024; NATURAL register
// allocation (no min-waves hint — R4's forced (256,4) spilled: VGPR 64,
// WRITE_SIZE 109 MB). 32-key K-tiles in LDS (chunk-major, global_load_lds,
// dbuf, ONE barrier/tile). V direct global->reg issued before the prefetch.
// P transpose via wave-private LDS. Scale pre-folded into Q.
__global__ __launch_bounds__(256) void mla_attn(
    const _Float16* __restrict__ qn,   // [T, NH*128]
    const _Float16* __restrict__ qp,   // [T, NH*64]  roped
    const _Float16* __restrict__ kn,   // [T, NH*128]
    const _Float16* __restrict__ kr,   // [T, 64]     roped
    const _Float16* __restrict__ vT,   // [NH*128, T]
    _Float16* __restrict__ out)        // [T, NH*128]
{
  __shared__ __attribute__((aligned(16))) _Float16 Ks[2][768 * 8];
  __shared__ __attribute__((aligned(16))) _Float16 Ps[4][16][40];

  const int bid = blockIdx.x;
  const int b = bid >> 9;
  const int u = bid & 511;
  const int h = u >> 5;
  const int xq = u & 31;
  const int q32 = b ? (31 - xq) : xq;   // complementary pairing across batches
  const int qb = q32 * 64;
  const int tok0 = b * S_LEN;

  const int tid = threadIdx.x;
  const int lane = tid & 63;
  const int wave = tid >> 6;
  const int m16 = lane & 15;
  const int quad = lane >> 4;
  const int R0 = qb + wave * 16;        // this wave's first q-row

  auto stageK = [&](int buf, int kbase) {
#pragma unroll
    for (int j = 0; j < 3; ++j) {
      const int i = wave * 3 + j;             // instr 0..11
      const int ch = i * 2 + (lane >> 5);     // wave-uniform side of 16
      const int key = lane & 31;
      const _Float16* g = (ch < 16)
          ? kn + (size_t)(tok0 + kbase + key) * 2048 + h * 128 + ch * 8
          : kr + (size_t)(tok0 + kbase + key) * 64 + (ch - 16) * 8;
      async16(g, &Ks[buf][i * 512]);
    }
  };

  // ---- Q fragments (A-layout), scale pre-folded ----
  const _Float16 hscale = (_Float16)0.07216878364870323f;  // 1/sqrt(192)
  f16x8 qf[6];
  {
    const size_t t = (size_t)(tok0 + R0 + m16);
#pragma unroll
    for (int kk = 0; kk < 4; ++kk)
      qf[kk] = *(const f16x8*)(qn + t * 2048 + h * 128 + kk * 32 + quad * 8);
#pragma unroll
    for (int kk = 0; kk < 2; ++kk)
      qf[4 + kk] = *(const f16x8*)(qp + t * 1024 + h * 64 + kk * 32 + quad * 8);
#pragma unroll
    for (int kk = 0; kk < 6; ++kk)
#pragma unroll
      for (int z = 0; z < 8; ++z) qf[kk][z] = qf[kk][z] * hscale;
  }

  const fx4 fz = {0.f, 0.f, 0.f, 0.f};
  fx4 oacc[8];
#pragma unroll
  for (int n = 0; n < 8; ++n) oacc[n] = fz;
  float mst[4], lst[4];
#pragma unroll
  for (int r = 0; r < 4; ++r) { mst[r] = -3.0e38f; lst[r] = 0.f; }

  const int nkt = qb / 32 + 2;               // key tiles: 0 .. qb+63

  stageK(0, 0);
  for (int kt = 0; kt < nkt; ++kt) {
    const int kbase = kt * 32;
    __syncthreads();                          // buf[kt&1] ready (in flight last iter)
    const bool live = (kbase <= R0 + 15);

    // V loads BEFORE prefetch-issue (vmcnt completes in order)
    f16x8 vf[8];
    if (live) {
#pragma unroll
      for (int n8 = 0; n8 < 8; ++n8)
        vf[n8] = *(const f16x8*)(vT + (size_t)(h * 128 + n8 * 16 + m16) * TOKENS +
                                 tok0 + kbase + quad * 8);
    }
    if (kt + 1 < nkt) stageK((kt + 1) & 1, kbase + 32);

    if (!live) continue;                      // fully-masked tile for this wave
    const _Float16* ks = Ks[kt & 1];

    // ---- S = Q K^T : 16 rows x 32 keys ----
    fx4 sc0 = fz, sc1 = fz;
#pragma unroll
    for (int kk = 0; kk < 6; ++kk) {
      f16x8 kf0 = *(const f16x8*)(&ks[((kk * 4 + quad) * 32 + m16) * 8]);
      f16x8 kf1 = *(const f16x8*)(&ks[((kk * 4 + quad) * 32 + 16 + m16) * 8]);
      sc0 = __builtin_amdgcn_mfma_f32_16x16x32_f16(qf[kk], kf0, sc0, 0, 0, 0);
      sc1 = __builtin_amdgcn_mfma_f32_16x16x32_f16(qf[kk], kf1, sc1, 0, 0, 0);
    }

    // ---- online softmax (C/D layout: row = quad*4+r, col = n*16+m16) ----
    const bool needmask = (kbase + 31 > R0);
    float alpha[4];
#pragma unroll
    for (int r = 0; r < 4; ++r) {
      float v0 = sc0[r];
      float v1 = sc1[r];
      if (needmask) {
        const int qrow = R0 + quad * 4 + r;
        if (kbase + m16 > qrow)      v0 = -3.0e38f;
        if (kbase + 16 + m16 > qrow) v1 = -3.0e38f;
      }
      float mx = fmaxf(v0, v1);
#pragma unroll
      for (int d = 1; d < 16; d <<= 1) mx = fmaxf(mx, __shfl_xor(mx, d));
      const float mn = fmaxf(mst[r], mx);
      const float al = __expf(mst[r] - mn);
      const float p0 = __expf(v0 - mn);
      const float p1 = __expf(v1 - mn);
      float ls = p0 + p1;
#pragma unroll
      for (int d = 1; d < 16; d <<= 1) ls += __shfl_xor(ls, d);
      mst[r] = mn;
      lst[r] = lst[r] * al + ls;
      alpha[r] = al;
      _Float16* pr = &Ps[wave][quad * 4 + r][0];
      pr[m16] = (_Float16)p0;
      pr[16 + m16] = (_Float16)p1;
    }
#pragma unroll
    for (int n8 = 0; n8 < 8; ++n8)
#pragma unroll
      for (int r = 0; r < 4; ++r) oacc[n8][r] *= alpha[r];

    // ---- O += P V  (P via wave-private LDS -> A-layout; V from regs) ----
    f16x8 pf = *(const f16x8*)(&Ps[wave][m16][quad * 8]);
#pragma unroll
    for (int n8 = 0; n8 < 8; ++n8)
      oacc[n8] = __builtin_amdgcn_mfma_f32_16x16x32_f16(pf, vf[n8], oacc[n8], 0, 0, 0);
  }

  // ---- epilogue ----
  float inv[4];
#pragma unroll
  for (int r = 0; r < 4; ++r) inv[r] = 1.0f / lst[r];
#pragma unroll
  for (int n8 = 0; n8 < 8; ++n8) {
#pragma unroll
    for (int r = 0; r < 4; ++r) {
      const size_t t = (size_t)(tok0 + R0 + quad * 4 + r);
      out[t * 2048 + h * 128 + n8 * 16 + m16] = (_Float16)(oacc[n8][r] * inv[r]);
    }
  }
}

// ---------------- launch ----------------------------------------------------
extern "C" void kernel_launch(void* const* d_in, const int* in_sizes, int n_in,
                              void* d_out, int out_size, void* d_ws, size_t ws_size,
                              hipStream_t stream) {
  const float* x         = (const float*)d_in[0];
  const float* wq_down   = (const float*)d_in[1];
  const float* q_norm_w  = (const float*)d_in[2];
  const float* wq_up     = (const float*)d_in[3];
  const float* wq_rope   = (const float*)d_in[4];
  const float* wkv_down  = (const float*)d_in[5];
  const float* kv_norm_w = (const float*)d_in[6];
  const float* wkv_up    = (const float*)d_in[7];
  const float* wk_rope   = (const float*)d_in[8];
  const float* wo        = (const float*)d_in[9];
  float* out = (float*)d_out;

  char* ws = (char*)d_ws;
  size_t off = 0;
  auto alloc = [&](size_t bytes) {
    char* p = ws + off;
    off += (bytes + 255) & ~(size_t)255;
    return p;
  };
  _Float16* x_h     = (_Float16*)alloc((size_t)TOKENS * DIM * 2);
  _Float16* wdown_h = (_Float16*)alloc((size_t)2176 * DIM * 2);  // wqd|wkvd|wkr + 64 pad rows
  _Float16* wquqr_h = (_Float16*)alloc((size_t)3072 * QR * 2);   // wq_up | wq_rope
  _Float16* wkvu_h  = (_Float16*)alloc((size_t)NH * 256 * KVR * 2);
  _Float16* wo_h    = (_Float16*)alloc((size_t)DIM * NH * DV * 2);
  _Float16* qc_h    = (_Float16*)alloc((size_t)TOKENS * QR * 2);
  _Float16* kvc_h   = (_Float16*)alloc((size_t)TOKENS * KVR * 2);
  _Float16* qnope_h = (_Float16*)alloc((size_t)TOKENS * 2048 * 2);
  _Float16* qpe_h   = (_Float16*)alloc((size_t)TOKENS * 1024 * 2);
  _Float16* knope_h = (_Float16*)alloc((size_t)TOKENS * 2048 * 2);
  _Float16* vT_h    = (_Float16*)alloc((size_t)2048 * TOKENS * 2);
  _Float16* krope_h = (_Float16*)alloc((size_t)TOKENS * DR * 2);
  _Float16* attn_h  = (_Float16*)alloc((size_t)TOKENS * 2048 * 2);

  // ---- one fused conversion dispatch ----
  CvtSegs cs;
  const float* srcs[8] = {x, wq_down, wkv_down, wk_rope, wq_up, wq_rope, wkv_up, wo};
  _Float16* dsts[8] = {x_h, wdown_h, wdown_h + (size_t)1536 * DIM,
                       wdown_h + (size_t)2048 * DIM, wquqr_h,
                       wquqr_h + (size_t)2048 * QR, wkvu_h, wo_h};
  const size_t ns[8] = {(size_t)TOKENS * DIM, (size_t)QR * DIM, (size_t)KVR * DIM,
                        (size_t)DR * DIM, (size_t)2048 * QR, (size_t)1024 * QR,
                        (size_t)NH * 256 * KVR, (size_t)DIM * NH * DV};
  int cum = 0;
  for (int i = 0; i < 8; ++i) {
    cs.src[i] = srcs[i];
    cs.dst[i] = dsts[i];
    cs.n4[i] = (int)(ns[i] / 4);
    cs.cum[i] = cum;
    cum += (cs.n4[i] + 255) / 256;
  }
  cs.cum[8] = cum;
  cvt_all<<<dim3(cum), 256, 0, stream>>>(cs);

  // down-fused: x -> qc | kvc | krope   (N=2112 in 17 tiles, 64-row M-tiles)
  gemm_nt<5, 64><<<dim3(17, TOKENS / 64), 256, 0, stream>>>(
      x_h, wdown_h, qc_h, kvc_h, krope_h, 2112, DIM);
  rmsnorm_ip<QR><<<dim3(TOKENS), 256, 0, stream>>>(qc_h, q_norm_w);
  rmsnorm_ip<KVR><<<dim3(TOKENS), 256, 0, stream>>>(kvc_h, kv_norm_w);
  rope_k<<<dim3(TOKENS * 32 / 256), 256, 0, stream>>>(krope_h);
  // q up fused: qc -> qnope | qpe (N=3072)
  gemm_nt<3, 128><<<dim3(24, TOKENS / 128), 256, 0, stream>>>(
      qc_h, wquqr_h, qnope_h, qpe_h, nullptr, 3072, QR);
  rope_q<<<dim3(TOKENS * NH * 32 / 256), 256, 0, stream>>>(qpe_h);
  // kv up-projection, split epilogue: k_nope natural + V transposed
  gemm_nt<2, 128><<<dim3(32, TOKENS / 128), 256, 0, stream>>>(
      kvc_h, wkvu_h, knope_h, vT_h, nullptr, 4096, KVR);
  // attention (grid 1024; natural VGPR -> 3-4 blocks/CU without spill)
  mla_attn<<<dim3(1024), 256, 0, stream>>>(qnope_h, qpe_h, knope_h, krope_h, vT_h, attn_h);
  // output projection (fp32 out, 64-row M-tiles -> grid 1024)
  gemm_nt<1, 64><<<dim3(16, TOKENS / 64), 256, 0, stream>>>(
      attn_h, wo_h, out, nullptr, nullptr, 2048, DIM);
}

// Round 6
// 669.107 us; speedup vs baseline: 1.1157x; 1.0203x over previous
//
#include <hip/hip_runtime.h>
#include <stdint.h>

typedef _Float16 f16x8 __attribute__((ext_vector_type(8)));
typedef _Float16 f16x4 __attribute__((ext_vector_type(4)));
typedef float fx4 __attribute__((ext_vector_type(4)));

static constexpr int S_LEN = 2048;
static constexpr int BATCH = 2;
static constexpr int TOKENS = BATCH * S_LEN;   // 4096
static constexpr int DIM = 2048;
static constexpr int NH = 16;
static constexpr int QR = 1536;
static constexpr int KVR = 512;
static constexpr int DN = 128;
static constexpr int DR = 64;
static constexpr int DV = 128;

// async global->LDS, 16B per lane; LDS dest = wave-uniform base, HW adds lane*16
__device__ __forceinline__ void async16(const _Float16* g, _Float16* lds_base_uniform) {
  __builtin_amdgcn_global_load_lds(
      (const __attribute__((address_space(1))) void*)g,
      (__attribute__((address_space(3))) void*)lds_base_uniform, 16, 0, 0);
}

// ---------------- fused f32 -> f16 conversion (all tensors, one dispatch) ---
struct CvtSegs {
  const float* src[8];
  _Float16* dst[8];
  int n4[8];
  int cum[9];
};
__global__ __launch_bounds__(256) void cvt_all(CvtSegs s) {
  const int b = blockIdx.x;
  int seg = 0;
#pragma unroll
  for (int k = 0; k < 7; ++k) seg += (b >= s.cum[seg + 1]) ? 1 : 0;
  const int i = (b - s.cum[seg]) * 256 + threadIdx.x;
  if (i >= s.n4[seg]) return;
  fx4 v = *(const fx4*)(s.src[seg] + (size_t)i * 4);
  f16x4 o;
  o[0] = (_Float16)v[0]; o[1] = (_Float16)v[1];
  o[2] = (_Float16)v[2]; o[3] = (_Float16)v[3];
  *(f16x4*)(s.dst[seg] + (size_t)i * 4) = o;
}

// ---------------- NT GEMM, dbuf LDS, one barrier/K-iter, TM x 128 tile -----
// C[M,N] = A[M,K] * W[N,K]^T.   All launches TM=128 (TM=64's 8-MFMA:6-stage
// ratio regressed in R5).
// MODE 1: f32 C0.  MODE 2: split knope[T,2048] + vT[2048,T].
// MODE 3: split qnope[.,2048] + qpe[.,1024].
// MODE 5: down-fused split qc[.,1536] | kvc[.,512] | krope[.,64] (N=2112).
template <int MODE, int TM>
__global__ __launch_bounds__(256)
void gemm_nt(const _Float16* __restrict__ A, const _Float16* __restrict__ W,
             void* __restrict__ C0v, void* __restrict__ C1v, void* __restrict__ C2v,
             int N, int K) {
  constexpr int NI = TM / 32;                 // acc tiles in M per wave
  __shared__ __attribute__((aligned(16))) _Float16 As[2][TM * 32];
  __shared__ __attribute__((aligned(16))) _Float16 Ws[2][128 * 32];
  const int tid = threadIdx.x;
  const int lane = tid & 63;
  const int wave = tid >> 6;
  const int wr = (wave >> 1) * (TM / 2);
  const int wc = (wave & 1) * 64;
  const int m16 = lane & 15;
  const int quad = lane >> 4;
  const int m0 = blockIdx.y * TM;
  const int n0 = blockIdx.x * 128;

  auto stage = [&](int buf, int k0) {
#pragma unroll
    for (int p = 0; p < TM / 64; ++p) {       // A: TM*4 chunks of 16B
      const int cb = p * 256 + wave * 64;
      const int ch = cb + lane;
      const int r = ch >> 2;
      const int c8 = (ch & 3) * 8;
      async16(A + (size_t)(m0 + r) * K + k0 + c8, &As[buf][cb * 8]);
    }
#pragma unroll
    for (int p = 0; p < 2; ++p) {             // W: 512 chunks
      const int cb = p * 256 + wave * 64;
      const int ch = cb + lane;
      const int r = ch >> 2;
      const int c8 = (ch & 3) * 8;
      async16(W + (size_t)(n0 + r) * K + k0 + c8, &Ws[buf][cb * 8]);
    }
  };

  const fx4 fz = {0.f, 0.f, 0.f, 0.f};
  fx4 acc[NI][4];
#pragma unroll
  for (int i = 0; i < NI; ++i)
#pragma unroll
    for (int j = 0; j < 4; ++j) acc[i][j] = fz;

  const int nkt = K >> 5;
  stage(0, 0);
  for (int kt = 0; kt < nkt; ++kt) {
    __syncthreads();
    if (kt + 1 < nkt) stage((kt + 1) & 1, (kt + 1) * 32);
    const _Float16* as = As[kt & 1];
    const _Float16* ws = Ws[kt & 1];
    f16x8 af[NI], wf[4];
#pragma unroll
    for (int i = 0; i < NI; ++i)
      af[i] = *(const f16x8*)(&as[(wr + i * 16 + m16) * 32 + quad * 8]);
#pragma unroll
    for (int j = 0; j < 4; ++j)
      wf[j] = *(const f16x8*)(&ws[(wc + j * 16 + m16) * 32 + quad * 8]);
#pragma unroll
    for (int i = 0; i < NI; ++i)
#pragma unroll
      for (int j = 0; j < 4; ++j)
        acc[i][j] = __builtin_amdgcn_mfma_f32_16x16x32_f16(af[i], wf[j], acc[i][j], 0, 0, 0);
  }

#pragma unroll
  for (int j = 0; j < 4; ++j) {
    const int col = n0 + wc + j * 16 + m16;
    if (MODE == 2) {
      _Float16* KN = (_Float16*)C0v;
      _Float16* VT = (_Float16*)C1v;
      const int head = col >> 8;
      const int sub = col & 255;
      if (sub < 128) {
#pragma unroll
        for (int i = 0; i < NI; ++i)
#pragma unroll
          for (int r = 0; r < 4; ++r)
            KN[(size_t)(m0 + wr + i * 16 + quad * 4 + r) * 2048 + head * 128 + sub] =
                (_Float16)acc[i][j][r];
      } else {
        const int dv = sub - 128;
#pragma unroll
        for (int i = 0; i < NI; ++i) {
          f16x4 v;
#pragma unroll
          for (int r = 0; r < 4; ++r) v[r] = (_Float16)acc[i][j][r];
          *(f16x4*)(&VT[(size_t)(head * 128 + dv) * TOKENS + m0 + wr + i * 16 + quad * 4]) = v;
        }
      }
    } else if (MODE == 3) {
#pragma unroll
      for (int i = 0; i < NI; ++i)
#pragma unroll
        for (int r = 0; r < 4; ++r) {
          const size_t row = (size_t)(m0 + wr + i * 16 + quad * 4 + r);
          if (col < 2048) ((_Float16*)C0v)[row * 2048 + col] = (_Float16)acc[i][j][r];
          else ((_Float16*)C1v)[row * 1024 + col - 2048] = (_Float16)acc[i][j][r];
        }
    } else if (MODE == 5) {
#pragma unroll
      for (int i = 0; i < NI; ++i)
#pragma unroll
        for (int r = 0; r < 4; ++r) {
          const size_t row = (size_t)(m0 + wr + i * 16 + quad * 4 + r);
          const _Float16 v = (_Float16)acc[i][j][r];
          if (col < 1536) ((_Float16*)C0v)[row * 1536 + col] = v;
          else if (col < 2048) ((_Float16*)C1v)[row * 512 + col - 1536] = v;
          else if (col < 2112) ((_Float16*)C2v)[row * 64 + col - 2048] = v;
        }
    } else {  // MODE 1: f32
      if (col < N) {
#pragma unroll
        for (int i = 0; i < NI; ++i)
#pragma unroll
          for (int r = 0; r < 4; ++r) {
            const size_t row = (size_t)(m0 + wr + i * 16 + quad * 4 + r);
            ((float*)C0v)[row * N + col] = acc[i][j][r];
          }
      }
    }
  }
}

// ---------------- in-place RMSNorm over f16 rows (fp32 math) ---------------
template <int NC>
__global__ __launch_bounds__(256) void rmsnorm_ip(_Float16* __restrict__ xx,
                                                  const float* __restrict__ w) {
  const int row = blockIdx.x;
  _Float16* p = xx + (size_t)row * NC;
  float ss = 0.f;
  for (int c = threadIdx.x; c < NC; c += 256) {
    const float v = (float)p[c];
    ss += v * v;
  }
#pragma unroll
  for (int d = 1; d < 64; d <<= 1) ss += __shfl_xor(ss, d);
  __shared__ float red[4];
  if ((threadIdx.x & 63) == 0) red[threadIdx.x >> 6] = ss;
  __syncthreads();
  const float rs = rsqrtf((red[0] + red[1] + red[2] + red[3]) * (1.0f / NC) + 1e-6f);
  for (int c = threadIdx.x; c < NC; c += 256)
    p[c] = (_Float16)((float)p[c] * rs * w[c]);
}

// ---------------- in-place RoPE (LLaMA interleaved pairs, d=64) ------------
__global__ void rope_q(_Float16* __restrict__ qpe) {  // [T, NH*64]
  const int idx = blockIdx.x * 256 + threadIdx.x;     // T*NH*32 threads
  const int t = idx >> 9;
  const int rem = idx & 511;
  const int hh = rem >> 5;
  const int i = rem & 31;
  const int s = t & (S_LEN - 1);
  const float fr = exp2f(-(float)i * 0.4152410118609203f);  // log2(1e4)/32
  const float ang = (float)s * fr;
  const float sn = sinf(ang), cs = cosf(ang);
  const size_t base = (size_t)t * (NH * DR) + hh * DR + 2 * i;
  const float x1 = (float)qpe[base];
  const float x2 = (float)qpe[base + 1];
  qpe[base] = (_Float16)(x1 * cs - x2 * sn);
  qpe[base + 1] = (_Float16)(x1 * sn + x2 * cs);
}

__global__ void rope_k(_Float16* __restrict__ kr) {  // [T, 64]
  const int idx = blockIdx.x * 256 + threadIdx.x;    // T*32 threads
  const int t = idx >> 5;
  const int i = idx & 31;
  const int s = t & (S_LEN - 1);
  const float fr = exp2f(-(float)i * 0.4152410118609203f);
  const float ang = (float)s * fr;
  const float sn = sinf(ang), cs = cosf(ang);
  const size_t base = (size_t)t * DR + 2 * i;
  const float x1 = (float)kr[base];
  const float x2 = (float)kr[base + 1];
  kr[base] = (_Float16)(x1 * cs - x2 * sn);
  kr[base + 1] = (_Float16)(x1 * sn + x2 * cs);
}

// ---------------- split-K causal flash attention ---------------------------
// R3's proven wave shape (4 waves x 32 q-rows = 128-row q-tile, 32-key LDS
// tiles, one barrier/tile, dbuf global_load_lds staging) but the key range is
// halved across TWO blocks per (b,h,q-tile): grid 1024 -> 4 independent
// barrier-groups per CU, so one block's barrier drain overlaps the others'
// compute. Partials (unnormalized O' f16, m/l f32) merged by attn_combine.
__global__ __launch_bounds__(256) void mla_attn_split(
    const _Float16* __restrict__ qn,   // [T, NH*128]
    const _Float16* __restrict__ qp,   // [T, NH*64]  roped
    const _Float16* __restrict__ kn,   // [T, NH*128]
    const _Float16* __restrict__ kr,   // [T, 64]     roped
    const _Float16* __restrict__ vT,   // [NH*128, T]
    _Float16* __restrict__ Op,         // [2][T][2048] unnormalized partial O
    float* __restrict__ ml)            // [2][T][16][2] (m, l)
{
  __shared__ __attribute__((aligned(16))) _Float16 Ks[2][768 * 8];
  __shared__ __attribute__((aligned(16))) _Float16 Ps[4][32][40];

  const int bid = blockIdx.x;
  const int sp = bid >> 9;              // key-split index
  const int v = bid & 511;
  const int b = v >> 8;
  const int u = v & 255;
  const int h = u >> 4;
  const int xq = u & 15;
  const int q16 = b ? (15 - xq) : xq;   // complementary pairing across batches
  const int qb = q16 * 128;
  const int tok0 = b * S_LEN;

  const int tid = threadIdx.x;
  const int lane = tid & 63;
  const int wave = tid >> 6;
  const int m16 = lane & 15;
  const int quad = lane >> 4;
  const int R0 = qb + wave * 32;        // this wave's first q-row

  const int nkt = qb / 32 + 4;          // total key tiles (even: 4*q16+4)
  const int half = nkt >> 1;
  const int t0 = sp ? half : 0;
  const int t1 = sp ? nkt : half;

  auto stageK = [&](int buf, int kbase) {
#pragma unroll
    for (int j = 0; j < 3; ++j) {
      const int i = wave * 3 + j;             // instr 0..11
      const int ch = i * 2 + (lane >> 5);     // wave-uniform side of 16
      const int key = lane & 31;
      const _Float16* g = (ch < 16)
          ? kn + (size_t)(tok0 + kbase + key) * 2048 + h * 128 + ch * 8
          : kr + (size_t)(tok0 + kbase + key) * 64 + (ch - 16) * 8;
      async16(g, &Ks[buf][i * 512]);
    }
  };

  // ---- Q fragments (A-layout), scale pre-folded ----
  const _Float16 hscale = (_Float16)0.07216878364870323f;  // 1/sqrt(192)
  f16x8 qf[2][6];
#pragma unroll
  for (int rg = 0; rg < 2; ++rg) {
    const size_t t = (size_t)(tok0 + R0 + rg * 16 + m16);
#pragma unroll
    for (int kk = 0; kk < 4; ++kk)
      qf[rg][kk] = *(const f16x8*)(qn + t * 2048 + h * 128 + kk * 32 + quad * 8);
#pragma unroll
    for (int kk = 0; kk < 2; ++kk)
      qf[rg][4 + kk] = *(const f16x8*)(qp + t * 1024 + h * 64 + kk * 32 + quad * 8);
#pragma unroll
    for (int kk = 0; kk < 6; ++kk)
#pragma unroll
      for (int z = 0; z < 8; ++z) qf[rg][kk][z] = qf[rg][kk][z] * hscale;
  }

  const fx4 fz = {0.f, 0.f, 0.f, 0.f};
  fx4 oacc[2][8];
#pragma unroll
  for (int rg = 0; rg < 2; ++rg)
#pragma unroll
    for (int n = 0; n < 8; ++n) oacc[rg][n] = fz;
  float mst[2][4], lst[2][4];
#pragma unroll
  for (int rg = 0; rg < 2; ++rg)
#pragma unroll
    for (int r = 0; r < 4; ++r) { mst[rg][r] = -3.0e38f; lst[rg][r] = 0.f; }

  stageK(t0 & 1, t0 * 32);
  for (int kt = t0; kt < t1; ++kt) {
    const int kbase = kt * 32;
    __syncthreads();                          // buf[kt&1] ready
    const bool live = (kbase <= R0 + 31);

    // V loads BEFORE prefetch-issue (vmcnt completes in order)
    f16x8 vf[8];
    if (live) {
#pragma unroll
      for (int n8 = 0; n8 < 8; ++n8)
        vf[n8] = *(const f16x8*)(vT + (size_t)(h * 128 + n8 * 16 + m16) * TOKENS +
                                 tok0 + kbase + quad * 8);
    }
    if (kt + 1 < t1) stageK((kt + 1) & 1, kbase + 32);

    if (!live) continue;                      // fully-masked tile for this wave
    const _Float16* ks = Ks[kt & 1];

    // ---- S = Q K^T : 2 row-groups x 32 keys ----
    fx4 sc[2][2];
#pragma unroll
    for (int rg = 0; rg < 2; ++rg)
#pragma unroll
      for (int n = 0; n < 2; ++n) sc[rg][n] = fz;
#pragma unroll
    for (int kk = 0; kk < 6; ++kk) {
      f16x8 kf0 = *(const f16x8*)(&ks[((kk * 4 + quad) * 32 + m16) * 8]);
      f16x8 kf1 = *(const f16x8*)(&ks[((kk * 4 + quad) * 32 + 16 + m16) * 8]);
      sc[0][0] = __builtin_amdgcn_mfma_f32_16x16x32_f16(qf[0][kk], kf0, sc[0][0], 0, 0, 0);
      sc[0][1] = __builtin_amdgcn_mfma_f32_16x16x32_f16(qf[0][kk], kf1, sc[0][1], 0, 0, 0);
      sc[1][0] = __builtin_amdgcn_mfma_f32_16x16x32_f16(qf[1][kk], kf0, sc[1][0], 0, 0, 0);
      sc[1][1] = __builtin_amdgcn_mfma_f32_16x16x32_f16(qf[1][kk], kf1, sc[1][1], 0, 0, 0);
    }

    // ---- online softmax (C/D layout: row = quad*4+r, col = n*16+m16) ----
    const bool needmask = (kbase + 31 > R0);
#pragma unroll
    for (int rg = 0; rg < 2; ++rg) {
      float alpha[4];
#pragma unroll
      for (int r = 0; r < 4; ++r) {
        float v0 = sc[rg][0][r];
        float v1 = sc[rg][1][r];
        if (needmask) {
          const int qrow = R0 + rg * 16 + quad * 4 + r;
          if (kbase + m16 > qrow)      v0 = -3.0e38f;
          if (kbase + 16 + m16 > qrow) v1 = -3.0e38f;
        }
        float mx = fmaxf(v0, v1);
#pragma unroll
        for (int d = 1; d < 16; d <<= 1) mx = fmaxf(mx, __shfl_xor(mx, d));
        const float mn = fmaxf(mst[rg][r], mx);
        const float al = __expf(mst[rg][r] - mn);
        const float p0 = __expf(v0 - mn);
        const float p1 = __expf(v1 - mn);
        float ls = p0 + p1;
#pragma unroll
        for (int d = 1; d < 16; d <<= 1) ls += __shfl_xor(ls, d);
        mst[rg][r] = mn;
        lst[rg][r] = lst[rg][r] * al + ls;
        alpha[r] = al;
        _Float16* pr = &Ps[wave][rg * 16 + quad * 4 + r][0];
        pr[m16] = (_Float16)p0;
        pr[16 + m16] = (_Float16)p1;
      }
#pragma unroll
      for (int n8 = 0; n8 < 8; ++n8)
#pragma unroll
        for (int r = 0; r < 4; ++r) oacc[rg][n8][r] *= alpha[r];
    }

    // ---- O += P V  (P via wave-private LDS -> A-layout; V from regs) ----
    f16x8 pf0 = *(const f16x8*)(&Ps[wave][m16][quad * 8]);
    f16x8 pf1 = *(const f16x8*)(&Ps[wave][16 + m16][quad * 8]);
#pragma unroll
    for (int n8 = 0; n8 < 8; ++n8) {
      oacc[0][n8] = __builtin_amdgcn_mfma_f32_16x16x32_f16(pf0, vf[n8], oacc[0][n8], 0, 0, 0);
      oacc[1][n8] = __builtin_amdgcn_mfma_f32_16x16x32_f16(pf1, vf[n8], oacc[1][n8], 0, 0, 0);
    }
  }

  // ---- partial epilogue: unnormalized O' + (m,l) ----
#pragma unroll
  for (int rg = 0; rg < 2; ++rg) {
#pragma unroll
    for (int r = 0; r < 4; ++r) {
      const int t = tok0 + R0 + rg * 16 + quad * 4 + r;
      if (m16 == 0) {
        float* mp = ml + (((size_t)sp * TOKENS + t) * 16 + h) * 2;
        mp[0] = mst[rg][r];
        mp[1] = lst[rg][r];
      }
#pragma unroll
      for (int n8 = 0; n8 < 8; ++n8)
        Op[((size_t)sp * TOKENS + t) * 2048 + h * 128 + n8 * 16 + m16] =
            (_Float16)oacc[rg][n8][r];
    }
  }
}

// ---------------- combine the two key-splits -------------------------------
__global__ __launch_bounds__(256) void attn_combine(
    const _Float16* __restrict__ Op, const float* __restrict__ ml,
    _Float16* __restrict__ out) {
  const int t = blockIdx.x;
  const int tid = threadIdx.x;
  const int h = tid >> 4;
  const float* mp0 = ml + ((size_t)t * 16 + h) * 2;
  const float* mp1 = ml + (((size_t)TOKENS + t) * 16 + h) * 2;
  const float m0 = mp0[0], l0 = mp0[1];
  const float m1 = mp1[0], l1 = mp1[1];
  const float M = fmaxf(m0, m1);
  const float w0 = __expf(m0 - M), w1 = __expf(m1 - M);
  const float inv = 1.0f / (w0 * l0 + w1 * l1);
  const size_t base = (size_t)t * 2048 + tid * 8;
  f16x8 a = *(const f16x8*)(Op + base);
  f16x8 c = *(const f16x8*)(Op + (size_t)TOKENS * 2048 + base);
  f16x8 o;
#pragma unroll
  for (int z = 0; z < 8; ++z)
    o[z] = (_Float16)(((float)a[z] * w0 + (float)c[z] * w1) * inv);
  *(f16x8*)(out + base) = o;
}

// ---------------- launch ----------------------------------------------------
extern "C" void kernel_launch(void* const* d_in, const int* in_sizes, int n_in,
                              void* d_out, int out_size, void* d_ws, size_t ws_size,
                              hipStream_t stream) {
  const float* x         = (const float*)d_in[0];
  const float* wq_down   = (const float*)d_in[1];
  const float* q_norm_w  = (const float*)d_in[2];
  const float* wq_up     = (const float*)d_in[3];
  const float* wq_rope   = (const float*)d_in[4];
  const float* wkv_down  = (const float*)d_in[5];
  const float* kv_norm_w = (const float*)d_in[6];
  const float* wkv_up    = (const float*)d_in[7];
  const float* wk_rope   = (const float*)d_in[8];
  const float* wo        = (const float*)d_in[9];
  float* out = (float*)d_out;

  char* ws = (char*)d_ws;
  size_t off = 0;
  auto alloc = [&](size_t bytes) {
    char* p = ws + off;
    off += (bytes + 255) & ~(size_t)255;
    return p;
  };
  _Float16* x_h     = (_Float16*)alloc((size_t)TOKENS * DIM * 2);
  _Float16* wdown_h = (_Float16*)alloc((size_t)2176 * DIM * 2);  // wqd|wkvd|wkr + 64 pad rows
  _Float16* wquqr_h = (_Float16*)alloc((size_t)3072 * QR * 2);   // wq_up | wq_rope
  _Float16* wkvu_h  = (_Float16*)alloc((size_t)NH * 256 * KVR * 2);
  _Float16* wo_h    = (_Float16*)alloc((size_t)DIM * NH * DV * 2);
  _Float16* qc_h    = (_Float16*)alloc((size_t)TOKENS * QR * 2);
  _Float16* kvc_h   = (_Float16*)alloc((size_t)TOKENS * KVR * 2);
  _Float16* qnope_h = (_Float16*)alloc((size_t)TOKENS * 2048 * 2);
  _Float16* qpe_h   = (_Float16*)alloc((size_t)TOKENS * 1024 * 2);
  _Float16* knope_h = (_Float16*)alloc((size_t)TOKENS * 2048 * 2);
  _Float16* vT_h    = (_Float16*)alloc((size_t)2048 * TOKENS * 2);
  _Float16* krope_h = (_Float16*)alloc((size_t)TOKENS * DR * 2);
  _Float16* attn_h  = (_Float16*)alloc((size_t)TOKENS * 2048 * 2);

  // Attention partials ALIAS dead regions (no new ws): x_h+wdown_h+wquqr_h
  // (16.78+8.91+9.44 MB contiguous >= 33.55 MB needed) die after the qup GEMM;
  // qc_h (12.6 MB) dies after qup too and holds the 1 MB m/l array.
  _Float16* Opart = x_h;
  float* mlbuf = (float*)qc_h;

  // ---- one fused conversion dispatch ----
  CvtSegs cs;
  const float* srcs[8] = {x, wq_down, wkv_down, wk_rope, wq_up, wq_rope, wkv_up, wo};
  _Float16* dsts[8] = {x_h, wdown_h, wdown_h + (size_t)1536 * DIM,
                       wdown_h + (size_t)2048 * DIM, wquqr_h,
                       wquqr_h + (size_t)2048 * QR, wkvu_h, wo_h};
  const size_t ns[8] = {(size_t)TOKENS * DIM, (size_t)QR * DIM, (size_t)KVR * DIM,
                        (size_t)DR * DIM, (size_t)2048 * QR, (size_t)1024 * QR,
                        (size_t)NH * 256 * KVR, (size_t)DIM * NH * DV};
  int cum = 0;
  for (int i = 0; i < 8; ++i) {
    cs.src[i] = srcs[i];
    cs.dst[i] = dsts[i];
    cs.n4[i] = (int)(ns[i] / 4);
    cs.cum[i] = cum;
    cum += (cs.n4[i] + 255) / 256;
  }
  cs.cum[8] = cum;
  cvt_all<<<dim3(cum), 256, 0, stream>>>(cs);

  // down-fused: x -> qc | kvc | krope   (N=2112, 128x128 tiles, grid 544)
  gemm_nt<5, 128><<<dim3(17, TOKENS / 128), 256, 0, stream>>>(
      x_h, wdown_h, qc_h, kvc_h, krope_h, 2112, DIM);
  rmsnorm_ip<QR><<<dim3(TOKENS), 256, 0, stream>>>(qc_h, q_norm_w);
  rmsnorm_ip<KVR><<<dim3(TOKENS), 256, 0, stream>>>(kvc_h, kv_norm_w);
  rope_k<<<dim3(TOKENS * 32 / 256), 256, 0, stream>>>(krope_h);
  // q up fused: qc -> qnope | qpe (N=3072)
  gemm_nt<3, 128><<<dim3(24, TOKENS / 128), 256, 0, stream>>>(
      qc_h, wquqr_h, qnope_h, qpe_h, nullptr, 3072, QR);
  rope_q<<<dim3(TOKENS * NH * 32 / 256), 256, 0, stream>>>(qpe_h);
  // kv up-projection, split epilogue: k_nope natural + V transposed
  gemm_nt<2, 128><<<dim3(32, TOKENS / 128), 256, 0, stream>>>(
      kvc_h, wkvu_h, knope_h, vT_h, nullptr, 4096, KVR);
  // attention: key-split x2 -> grid 1024 (4 blocks/CU), then combine
  mla_attn_split<<<dim3(1024), 256, 0, stream>>>(
      qnope_h, qpe_h, knope_h, krope_h, vT_h, Opart, mlbuf);
  attn_combine<<<dim3(TOKENS), 256, 0, stream>>>(Opart, mlbuf, attn_h);
  // output projection (fp32 out, 128x128 tiles, grid 512)
  gemm_nt<1, 128><<<dim3(16, TOKENS / 128), 256, 0, stream>>>(
      attn_h, wo_h, out, nullptr, nullptr, 2048, DIM);
}